// Round 2
// baseline (71816.345 us; speedup 1.0000x reference)
//
#include <hip/hip_runtime.h>
#include <stdint.h>

// TLSTM: batch-1 LSTM, T=16384 steps, IN=512, H=1024, OUT=64.
// Persistent-ish design: 128 WGs x 512 threads. WG b owns h-elements
// {8b..8b+7}; wave w computes all 4 gate rows of elem 8b+w, weights in
// registers (96 floats/lane, loaded once). Cross-WG h exchange per step via
// tagged 64-bit {step,value} words in d_ws, relaxed agent-scope atomics
// (tag travels with data => no fences). Double-buffered by parity; the
// all-to-all dependence bounds skew to 1 step so 2 buffers suffice.
// Poll loop is 2-deep software-pipelined (check snapshot k while k+1 is in
// flight) to cut detection quantization from ~1 RT to ~RT/2.

typedef unsigned long long u64;

#define T_STEPS 16384
#define IN_DIM  512
#define H_DIM   1024
#define OUT_DIM 64
#define NWG     128
#define WGSZ    512

__device__ __forceinline__ float sigf(float x) {
    return 1.0f / (1.0f + __expf(-x));
}
__device__ __forceinline__ float tanh_fast(float x) {
    return 2.0f / (1.0f + __expf(-2.0f * x)) - 1.0f;
}
__device__ __forceinline__ float dot4(float4 a, float4 b) {
    return a.x * b.x + a.y * b.y + a.z * b.z + a.w * b.w;
}

__global__ __launch_bounds__(WGSZ, 1) void lstm_seq(
    const float* __restrict__ X,
    const float* __restrict__ W_ih,
    const float* __restrict__ W_hh,
    const float* __restrict__ b_ih,
    const float* __restrict__ b_hh,
    u64* __restrict__ hbuf)   // [2][H_DIM] tagged words in d_ws
{
    const int b    = blockIdx.x;      // 0..127
    const int tid  = threadIdx.x;     // 0..511
    const int w    = tid >> 6;        // wave id 0..7
    const int lane = tid & 63;
    const int elem = 8 * b + w;       // h index this wave produces

    __shared__ float h_lds[2][H_DIM];   // 8 KiB

    // ---- one-time: weights into registers ----
    // lane covers k = c*256 + lane*4 + {0..3} (coalesced float4 loads,
    // conflict-light ds_read_b128 later).
    float4 wh[4][4];   // [gate][chunk] over H_DIM=1024
    float4 wx[4][2];   // [gate][chunk] over IN_DIM=512
    float  bias_g[4];
    #pragma unroll
    for (int g = 0; g < 4; ++g) {
        const int row = g * H_DIM + elem;
        #pragma unroll
        for (int c = 0; c < 4; ++c)
            wh[g][c] = *(const float4*)(W_hh + (size_t)row * H_DIM + (c * 256 + lane * 4));
        #pragma unroll
        for (int c = 0; c < 2; ++c)
            wx[g][c] = *(const float4*)(W_ih + (size_t)row * IN_DIM + (c * 256 + lane * 4));
        bias_g[g] = b_ih[row] + b_hh[row];
    }

    float c_state = 0.0f;

    for (int t = 0; t < T_STEPS; ++t) {
        const int p = t & 1;
        const unsigned want = (unsigned)t;

        // ---- issue h[t] polls first (2 words/thread, 2-deep pipeline) ----
        const u64* src = hbuf + (size_t)p * H_DIM + (tid << 1);
        u64 a0 = __hip_atomic_load(src + 0, __ATOMIC_RELAXED, __HIP_MEMORY_SCOPE_AGENT);
        u64 a1 = __hip_atomic_load(src + 1, __ATOMIC_RELAXED, __HIP_MEMORY_SCOPE_AGENT);
        u64 b0 = __hip_atomic_load(src + 0, __ATOMIC_RELAXED, __HIP_MEMORY_SCOPE_AGENT);
        u64 b1 = __hip_atomic_load(src + 1, __ATOMIC_RELAXED, __HIP_MEMORY_SCOPE_AGENT);

        // ---- x-part of the 4 gate dots, overlapped with poll flight ----
        // (X is read-only: plain cached loads, wave-coalesced, no LDS/barrier)
        const float* xrow = X + (size_t)t * IN_DIM;
        const float4 xq0 = *(const float4*)(xrow + lane * 4);
        const float4 xq1 = *(const float4*)(xrow + 256 + lane * 4);
        float acc0 = dot4(wx[0][0], xq0) + dot4(wx[0][1], xq1);
        float acc1 = dot4(wx[1][0], xq0) + dot4(wx[1][1], xq1);
        float acc2 = dot4(wx[2][0], xq0) + dot4(wx[2][1], xq1);
        float acc3 = dot4(wx[3][0], xq0) + dot4(wx[3][1], xq1);

        // ---- finish polls ----
        for (;;) {
            const bool ok0 = (unsigned)(a0 >> 32) == want;   // waits vmcnt(2)
            const bool ok1 = (unsigned)(a1 >> 32) == want;
            if (ok0 && ok1) break;
            a0 = b0; a1 = b1;
            b0 = __hip_atomic_load(src + 0, __ATOMIC_RELAXED, __HIP_MEMORY_SCOPE_AGENT);
            b1 = __hip_atomic_load(src + 1, __ATOMIC_RELAXED, __HIP_MEMORY_SCOPE_AGENT);
        }
        h_lds[p][(tid << 1) + 0] = __uint_as_float((unsigned)(a0 & 0xffffffffu));
        h_lds[p][(tid << 1) + 1] = __uint_as_float((unsigned)(a1 & 0xffffffffu));
        __syncthreads();   // one barrier per step

        // ---- h-part of the 4 gate dots ----
        const float4* h4 = (const float4*)(&h_lds[p][0]);
        #pragma unroll
        for (int c = 0; c < 4; ++c) {
            const float4 hv = h4[c * 64 + lane];
            acc0 += dot4(wh[0][c], hv);
            acc1 += dot4(wh[1][c], hv);
            acc2 += dot4(wh[2][c], hv);
            acc3 += dot4(wh[3][c], hv);
        }

        // ---- full-wave butterfly reduce ----
        #pragma unroll
        for (int off = 32; off >= 1; off >>= 1) {
            acc0 += __shfl_xor(acc0, off);
            acc1 += __shfl_xor(acc1, off);
            acc2 += __shfl_xor(acc2, off);
            acc3 += __shfl_xor(acc3, off);
        }

        // ---- combine (all lanes; avoids divergent region) ----
        const float ii = sigf(acc0 + bias_g[0]);
        const float ff = sigf(acc1 + bias_g[1]);
        const float gg = tanh_fast(acc2 + bias_g[2]);
        const float oo = sigf(acc3 + bias_g[3]);
        const float cn = ff * c_state + ii * gg;
        c_state = cn;
        const float hn = oo * tanh_fast(cn);

        if (lane == 0) {
            const u64 word = ((u64)(unsigned)(t + 1) << 32)
                           | (u64)__float_as_uint(hn);
            __hip_atomic_store(hbuf + (size_t)((t + 1) & 1) * H_DIM + elem,
                               word, __ATOMIC_RELAXED, __HIP_MEMORY_SCOPE_AGENT);
        }
        // No second barrier: next step's h_lds writes hit parity (t+1)&1;
        // reuse of parity p at t+2 is separated by the t+1 barrier.
    }
}

__global__ __launch_bounds__(256, 1) void lstm_head(
    const u64* __restrict__ hbuf,
    const float* __restrict__ W_lin,
    const float* __restrict__ b_lin,
    float* __restrict__ out)
{
    const int tid  = threadIdx.x;
    const int o    = tid >> 2;       // output index, 4 threads per output
    const int part = tid & 3;
    const u64* src = hbuf + (size_t)(T_STEPS & 1) * H_DIM;

    float sum = 0.f;
    const int k0 = part * 256;
    for (int k = k0; k < k0 + 256; k += 4) {
        const float4 wv = *(const float4*)(W_lin + (size_t)o * H_DIM + k);
        sum += wv.x * __uint_as_float((unsigned)src[k + 0])
             + wv.y * __uint_as_float((unsigned)src[k + 1])
             + wv.z * __uint_as_float((unsigned)src[k + 2])
             + wv.w * __uint_as_float((unsigned)src[k + 3]);
    }
    sum += __shfl_xor(sum, 1);
    sum += __shfl_xor(sum, 2);
    if (part == 0)
        out[o] = 1.0f / (1.0f + __expf(-(sum + b_lin[o])));
}

extern "C" void kernel_launch(void* const* d_in, const int* in_sizes, int n_in,
                              void* d_out, int out_size, void* d_ws, size_t ws_size,
                              hipStream_t stream) {
    const float* X     = (const float*)d_in[0];
    // d_in[1] Mask, d_in[2] Delta, d_in[3] dt: unused by the forward pass
    const float* W_ih  = (const float*)d_in[4];
    const float* W_hh  = (const float*)d_in[5];
    const float* b_ih  = (const float*)d_in[6];
    const float* b_hh  = (const float*)d_in[7];
    const float* W_lin = (const float*)d_in[8];
    const float* b_lin = (const float*)d_in[9];
    float* out = (float*)d_out;

    u64* hbuf = (u64*)d_ws;   // 2 * 1024 * 8B = 16 KiB used

    // init: both parity buffers = {tag=0, h=0.0f} (all zero bytes)
    hipMemsetAsync(hbuf, 0, 2 * H_DIM * sizeof(u64), stream);

    lstm_seq<<<NWG, WGSZ, 0, stream>>>(X, W_ih, W_hh, b_ih, b_hh, hbuf);
    lstm_head<<<1, 256, 0, stream>>>(hbuf, W_lin, b_lin, out);
}

// Round 3
// 50255.533 us; speedup vs baseline: 1.4290x; 1.4290x over previous
//
#include <hip/hip_runtime.h>
#include <stdint.h>

// TLSTM: batch-1 LSTM, T=16384, IN=512, H=1024, OUT=64.
// 256 WGs x 256 threads (1 WG/CU). Wave w of WG b owns h-elem 4b+w and its
// 4 gate rows; weights live in registers (96 floats/lane, loaded once).
// Cross-WG h exchange per step: 512 packed words {tag32 | bf16 h_odd<<16 |
// bf16 h_even} in d_ws, relaxed agent-scope atomics (tag travels with the
// data => no fences needed). Double-buffered by step parity.
// Serial-path design: X loads issued BEFORE poll loads (vmcnt drain hides
// them); x-dots computed per-thread before barrier A (hidden in poll skew);
// producer packs 4 values via LDS gather + barrier B (cost ~100cyc, buys
// 4x less exchange traffic than fp32-per-elem).

typedef unsigned long long u64;

#define T_STEPS 16384
#define IN_DIM  512
#define H_DIM   1024
#define NWG     256
#define NWORDS  512   // packed words per parity buffer

__device__ __forceinline__ float sigf(float x) {
    return 1.0f / (1.0f + __expf(-x));
}
__device__ __forceinline__ float tanh_fast(float x) {
    return 2.0f / (1.0f + __expf(-2.0f * x)) - 1.0f;
}
__device__ __forceinline__ float dot4(float4 a, float4 b) {
    return a.x * b.x + a.y * b.y + a.z * b.z + a.w * b.w;
}
__device__ __forceinline__ float bf16_lo(unsigned v) {   // low 16 bits -> f32
    return __uint_as_float(v << 16);
}
__device__ __forceinline__ float bf16_hi(unsigned v) {   // high 16 bits -> f32
    return __uint_as_float(v & 0xffff0000u);
}
__device__ __forceinline__ unsigned f32_to_bf16_bits(float f) {
    // round-to-nearest-even; h is bounded (|h|<1), no NaN/Inf path needed
    unsigned u = __float_as_uint(f);
    return (u + 0x7fffu + ((u >> 16) & 1u)) >> 16;
}

__global__ __launch_bounds__(256, 1) void lstm_seq(
    const float* __restrict__ X,
    const float* __restrict__ W_ih,
    const float* __restrict__ W_hh,
    const float* __restrict__ b_ih,
    const float* __restrict__ b_hh,
    u64* __restrict__ hbuf)   // [2][NWORDS] packed words in d_ws
{
    const int b    = blockIdx.x;      // 0..255
    const int tid  = threadIdx.x;     // 0..255
    const int w    = tid >> 6;        // wave id 0..3
    const int lane = tid & 63;
    const int elem = 4 * b + w;       // h index this wave produces

    __shared__ float h_lds[2][H_DIM];   // 8 KiB
    __shared__ float gatherv[4];        // per-wave h values for packing

    // ---- one-time: weights into registers ----
    float4 wh[4][4];   // [gate][chunk] over H_DIM=1024
    float4 wx[4][2];   // [gate][chunk] over IN_DIM=512
    float  bias_g[4];
    #pragma unroll
    for (int g = 0; g < 4; ++g) {
        const int row = g * H_DIM + elem;
        #pragma unroll
        for (int c = 0; c < 4; ++c)
            wh[g][c] = *(const float4*)(W_hh + (size_t)row * H_DIM + (c * 256 + lane * 4));
        #pragma unroll
        for (int c = 0; c < 2; ++c)
            wx[g][c] = *(const float4*)(W_ih + (size_t)row * IN_DIM + (c * 256 + lane * 4));
        bias_g[g] = b_ih[row] + b_hh[row];
    }

    float c_state = 0.0f;

    for (int t = 0; t < T_STEPS; ++t) {
        const int p = t & 1;
        const unsigned want = (unsigned)t;

        // ---- X loads FIRST: older in vmem queue than polls, so the poll's
        //      vmcnt drain hides their HBM latency completely ----
        const float* xrow = X + (size_t)t * IN_DIM;
        const float4 xq0 = *(const float4*)(xrow + lane * 4);
        const float4 xq1 = *(const float4*)(xrow + 256 + lane * 4);

        // ---- poll h[t]: 2 packed words/thread, RT-paced rounds ----
        const u64* src = hbuf + (size_t)p * NWORDS + (tid << 1);
        u64 a0 = __hip_atomic_load(src + 0, __ATOMIC_RELAXED, __HIP_MEMORY_SCOPE_AGENT);
        u64 a1 = __hip_atomic_load(src + 1, __ATOMIC_RELAXED, __HIP_MEMORY_SCOPE_AGENT);
        while (!((unsigned)(a0 >> 32) == want && (unsigned)(a1 >> 32) == want)) {
            a0 = __hip_atomic_load(src + 0, __ATOMIC_RELAXED, __HIP_MEMORY_SCOPE_AGENT);
            a1 = __hip_atomic_load(src + 1, __ATOMIC_RELAXED, __HIP_MEMORY_SCOPE_AGENT);
        }
        // unpack: word 2*tid -> elems {4tid, 4tid+1}, word 2*tid+1 -> {4tid+2, 4tid+3}
        {
            const unsigned v0 = (unsigned)a0, v1 = (unsigned)a1;
            float4 hv;
            hv.x = bf16_lo(v0); hv.y = bf16_hi(v0);
            hv.z = bf16_lo(v1); hv.w = bf16_hi(v1);
            *(float4*)(&h_lds[p][tid << 2]) = hv;   // contiguous: conflict-free
        }

        // ---- x-part dots: per-thread, before barrier (hidden in poll skew) ----
        float acc0 = dot4(wx[0][0], xq0) + dot4(wx[0][1], xq1);
        float acc1 = dot4(wx[1][0], xq0) + dot4(wx[1][1], xq1);
        float acc2 = dot4(wx[2][0], xq0) + dot4(wx[2][1], xq1);
        float acc3 = dot4(wx[3][0], xq0) + dot4(wx[3][1], xq1);

        __syncthreads();   // barrier A: h_lds[p] fully staged

        // ---- h-part dots ----
        const float4* h4 = (const float4*)(&h_lds[p][0]);
        #pragma unroll
        for (int c = 0; c < 4; ++c) {
            const float4 hv = h4[c * 64 + lane];
            acc0 += dot4(wh[0][c], hv);
            acc1 += dot4(wh[1][c], hv);
            acc2 += dot4(wh[2][c], hv);
            acc3 += dot4(wh[3][c], hv);
        }

        // ---- full-wave butterfly reduce ----
        #pragma unroll
        for (int off = 32; off >= 1; off >>= 1) {
            acc0 += __shfl_xor(acc0, off);
            acc1 += __shfl_xor(acc1, off);
            acc2 += __shfl_xor(acc2, off);
            acc3 += __shfl_xor(acc3, off);
        }

        // ---- combine (all lanes; uniform control flow) ----
        const float ii = sigf(acc0 + bias_g[0]);
        const float ff = sigf(acc1 + bias_g[1]);
        const float gg = tanh_fast(acc2 + bias_g[2]);
        const float oo = sigf(acc3 + bias_g[3]);
        const float cn = ff * c_state + ii * gg;
        c_state = cn;
        const float hn = oo * tanh_fast(cn);

        if (lane == 0) gatherv[w] = hn;
        __syncthreads();   // barrier B: gatherv ready
        // gatherv race-safety: next write happens after barrier A of step t+1,
        // which waits for threads 0/1 to finish reading below.

        if (tid < 2) {
            const unsigned lo = f32_to_bf16_bits(gatherv[2 * tid])
                              | (f32_to_bf16_bits(gatherv[2 * tid + 1]) << 16);
            const u64 word = ((u64)(unsigned)(t + 1) << 32) | (u64)lo;
            __hip_atomic_store(hbuf + (size_t)((t + 1) & 1) * NWORDS + 2 * b + tid,
                               word, __ATOMIC_RELAXED, __HIP_MEMORY_SCOPE_AGENT);
        }
    }
}

__global__ __launch_bounds__(256, 1) void lstm_head(
    const u64* __restrict__ hbuf,
    const float* __restrict__ W_lin,
    const float* __restrict__ b_lin,
    float* __restrict__ out)
{
    const int tid  = threadIdx.x;
    const int o    = tid >> 2;       // output index, 4 threads per output
    const int part = tid & 3;
    // T even -> final h is in parity-0 buffer (tag T, guaranteed by stream order)
    const u64* src = hbuf + (size_t)(T_STEPS & 1) * NWORDS;

    float sum = 0.f;
    const int j0 = part * 128;       // each part covers 128 packed words = 256 h
    for (int j = j0; j < j0 + 128; ++j) {
        const unsigned v = (unsigned)src[j];
        const float2 wv = *(const float2*)(W_lin + (size_t)o * H_DIM + 2 * j);
        sum += wv.x * bf16_lo(v) + wv.y * bf16_hi(v);
    }
    sum += __shfl_xor(sum, 1);
    sum += __shfl_xor(sum, 2);
    if (part == 0)
        out[o] = 1.0f / (1.0f + __expf(-(sum + b_lin[o])));
}

extern "C" void kernel_launch(void* const* d_in, const int* in_sizes, int n_in,
                              void* d_out, int out_size, void* d_ws, size_t ws_size,
                              hipStream_t stream) {
    const float* X     = (const float*)d_in[0];
    // d_in[1] Mask, d_in[2] Delta, d_in[3] dt: unused by the forward pass
    const float* W_ih  = (const float*)d_in[4];
    const float* W_hh  = (const float*)d_in[5];
    const float* b_ih  = (const float*)d_in[6];
    const float* b_hh  = (const float*)d_in[7];
    const float* W_lin = (const float*)d_in[8];
    const float* b_lin = (const float*)d_in[9];
    float* out = (float*)d_out;

    u64* hbuf = (u64*)d_ws;   // 2 * 512 * 8B = 8 KiB used

    // init: both parity buffers = {tag=0, h=0} (all zero bytes)
    hipMemsetAsync(hbuf, 0, 2 * NWORDS * sizeof(u64), stream);

    lstm_seq<<<NWG, 256, 0, stream>>>(X, W_ih, W_hh, b_ih, b_hh, hbuf);
    lstm_head<<<1, 256, 0, stream>>>(hbuf, W_lin, b_lin, out);
}